// Round 9
// baseline (1417.627 us; speedup 1.0000x reference)
//
#include <hip/hip_runtime.h>
#include <hip/hip_bf16.h>
#include <math.h>

// Fused decoder + cross-entropy on MI355X.
//   logits = x @ W^T  (4096 x 50257, K=1024), loss = mean(-log_softmax(logits)[y])
// R6..R9: GEMM restructured to kill the lockstep bubble diagnosed in R5 (35%
// MfmaUtil, 1 block/CU, reads serialized with MFMA by 8 barriers/K-tile):
//   - BK=32, THREE LDS buffers (96KB) rotating: read buf[u%3], prefetch-read
//     frags(u+1) from buf[(u+1)%3], stage(u+2) into buf[(u+2)%3] (disjoint).
//   - Fragment ping-pong: MFMA(u) consumes registers read LAST tile; this tile's
//     ds_reads (for u+1) issue before the MFMA cluster and complete under it.
//   - ONE barrier per K-tile: [stage(u+2); vmcnt(4); s_barrier; ds_read(u+1);
//     MFMA(u) x32]. vmcnt(4) (own u+1 loads landed) + barrier => ALL waves'
//     u+1 loads landed before any wave reads them. Reads of buf[u%3] complete
//     (FIFO LDS pipe + per-wave lgkmcnt before MFMA) hundreds of cycles before
//     the earliest stage(u+3) DMA can land there. Drain vmcnt(0) only at tail.
//   - Paired-row LDS layout: global [256][32] stored as [128][64] (row r ->
//     lds row r>>1, col (r&1)*32+c) + XOR swizzle cg ^= (R&7): ds_read_b128
//     spreads 64 lanes uniformly over all 8 bank-granules (conflict-free).
// History: R2 964us (gemm 690, Mfma 26%); R3 804 (552, 33%); R5 797 (540, 35%,
// per-phase interleave +2% only => phase-split is not the lever at 1 block/CU);
// R6/R7/R8 not run (GPU acquisition timeouts) — resubmitted unchanged.
// Tripwires: absmax!=0 -> race -> revert to R5 sync; VGPR>=160 -> spill ->
// single frag set; MfmaUtil ~35% with PASS -> pivot to 32x32x16 MFMA.

#define N_NODES 4096
#define D_EMB   1024
#define VOCAB   50257
#define VPAD    50432   // 197 * 256
#define NT      197     // 256-wide vocab tiles
#define KT32    32      // K-tiles of 32 (1024/32)

typedef __attribute__((ext_vector_type(8))) short short8;   // 8 bf16 (MFMA A/B frag)
typedef __attribute__((ext_vector_type(4))) float f32x4;    // MFMA C/D frag

__device__ __forceinline__ unsigned short f2bf(float f) {
  unsigned int x = __float_as_uint(f);
  x += 0x7fffu + ((x >> 16) & 1u);
  return (unsigned short)(x >> 16);
}

// ---------------- fp32 -> bf16 conversion: x then W (padded), one launch -------
__global__ void cvt_kernel(const float* __restrict__ x, const float* __restrict__ W,
                           unsigned short* __restrict__ Xb, unsigned short* __restrict__ Wb) {
  const long long XG  = (long long)N_NODES * (D_EMB / 8);      // x 16B-groups
  const long long TOT = XG + (long long)VPAD * (D_EMB / 8);    // + W groups
  for (long long gid = (long long)blockIdx.x * 256 + threadIdx.x; gid < TOT;
       gid += (long long)gridDim.x * 256) {
    short8 o;
    if (gid < XG) {
      long long e = gid << 3;
      const float4* p = (const float4*)(x + e);
      float4 u = p[0], v = p[1];
      o[0]=(short)f2bf(u.x); o[1]=(short)f2bf(u.y); o[2]=(short)f2bf(u.z); o[3]=(short)f2bf(u.w);
      o[4]=(short)f2bf(v.x); o[5]=(short)f2bf(v.y); o[6]=(short)f2bf(v.z); o[7]=(short)f2bf(v.w);
      *(short8*)(Xb + e) = o;
    } else {
      long long wg = gid - XG;
      long long e = wg << 3;
      int row = (int)(e >> 10);
      if (row < VOCAB) {
        const float4* p = (const float4*)(W + e);
        float4 u = p[0], v = p[1];
        o[0]=(short)f2bf(u.x); o[1]=(short)f2bf(u.y); o[2]=(short)f2bf(u.z); o[3]=(short)f2bf(u.w);
        o[4]=(short)f2bf(v.x); o[5]=(short)f2bf(v.y); o[6]=(short)f2bf(v.z); o[7]=(short)f2bf(v.w);
      } else {
        o[0]=0;o[1]=0;o[2]=0;o[3]=0;o[4]=0;o[5]=0;o[6]=0;o[7]=0;
      }
      *(short8*)(Wb + e) = o;
    }
  }
}

// ---------------- 256^2 MFMA GEMM, BK=32, 3-buffer, 1 barrier/K-tile ------------
#define GLD(SRC, DST)                                                              \
  __builtin_amdgcn_global_load_lds(                                                \
      (const __attribute__((address_space(1))) void*)(SRC),                        \
      (__attribute__((address_space(3))) void*)(DST), 16, 0, 0)

// stage K-tile U (A: 2 gloads, B: 2 gloads) into LDS buffer at elem offset BB
#define STAGE_T(U, BB)                                                             \
  do {                                                                             \
    const int _ko = (U) << 5;                                                      \
    GLD(Xb + aoff0 + _ko,          sh + (BB) + dstA);                              \
    GLD(Xb + aoff0 + 131072 + _ko, sh + (BB) + 4096 + dstA);                       \
    GLD(Wb + boff0 + _ko,          sh + (BB) + 8192 + dstA);                       \
    GLD(Wb + boff0 + 131072 + _ko, sh + (BB) + 12288 + dstA);                      \
  } while (0)

#define READ_FRAGS(BB, FA, FB)                                                     \
  do {                                                                             \
    const unsigned short* _A = sh + (BB) + aread;                                  \
    const unsigned short* _B = sh + (BB) + bread;                                  \
    _Pragma("unroll")                                                              \
    for (int ni = 0; ni < 4; ++ni) FB[ni] = *(const short8*)(_B + ni * 512);       \
    _Pragma("unroll")                                                              \
    for (int mi = 0; mi < 8; ++mi) FA[mi] = *(const short8*)(_A + mi * 512);       \
  } while (0)

#define MFMA32(FA, FB)                                                             \
  do {                                                                             \
    _Pragma("unroll")                                                              \
    for (int mi = 0; mi < 8; ++mi)                                                 \
      _Pragma("unroll")                                                            \
      for (int ni = 0; ni < 4; ++ni)                                               \
        acc[mi][ni] = __builtin_amdgcn_mfma_f32_16x16x32_bf16(FA[mi], FB[ni], acc[mi][ni], 0, 0, 0); \
  } while (0)

// one K-tile: stage(u+2) | vmcnt(4) | barrier | prefetch frags(u+1) | MFMA(u)
#define TILE(U, FCA, FCB, FNA, FNB)                                                \
  do {                                                                             \
    if ((U) + 2 < KT32) STAGE_T((U) + 2, bstage);                                  \
    if ((U) + 1 < KT32) {                                                          \
      if ((U) < KT32 - 2) { asm volatile("s_waitcnt vmcnt(4)" ::: "memory"); }     \
      else                { asm volatile("s_waitcnt vmcnt(0)" ::: "memory"); }     \
      __builtin_amdgcn_s_barrier();                                                \
      READ_FRAGS(bnext, FNA, FNB);                                                 \
      __builtin_amdgcn_sched_barrier(0);                                           \
    }                                                                              \
    __builtin_amdgcn_s_setprio(1);                                                 \
    MFMA32(FCA, FCB);                                                              \
    __builtin_amdgcn_s_setprio(0);                                                 \
    { int _t = bcur; bcur = bnext; bnext = bstage; bstage = _t; }                  \
  } while (0)

__global__ __launch_bounds__(512, 2) void gemm_stats_kernel(
    const unsigned short* __restrict__ Xb,
    const unsigned short* __restrict__ Wb,
    float2* __restrict__ partials)  // [N_NODES][NT]: (rowmax, sumexp) per vocab tile
{
  __shared__ __align__(16) unsigned short sh[49152];  // 96 KB = 3 x (A 16K + B 16K)

  const int tid  = threadIdx.x;
  const int lane = tid & 63;
  const int wid  = tid >> 6;    // 0..7
  const int wr   = wid >> 2;    // 0..1: rows wr*128..
  const int wcol = wid & 3;     // 0..3: cols wcol*64..
  const int g    = lane >> 4;   // 0..3
  const int r16  = lane & 15;

  const int bm0 = blockIdx.x * 256;
  const int bn0 = blockIdx.y * 256;

  // --- staging geometry: LDS [128][64] paired-row; slot (R,cg) holds global
  //     (row (R<<1)|(cgu>>2), col (cgu&3)*8) with cgu = cg ^ (R&7).
  //     Thread t, pass p: chunk idx = t + p*512; R = idx>>3; cg = idx&7.
  const int cgu   = (tid & 7) ^ ((tid >> 3) & 7);
  const int rl0   = ((tid >> 3) << 1) | (cgu >> 2);
  const int cgc   = (cgu & 3) << 3;
  const int aoff0 = (bm0 + rl0) * D_EMB + cgc;     // + 131072 for p=1 (+128 rows)
  const int boff0 = (bn0 + rl0) * D_EMB + cgc;
  const int dstA  = tid * 8;                       // + p*4096; B region +8192

  // --- fragment-read geometry: row ar -> R = ar>>1, cg = ((ar&1)*4+g) ^ (R&7);
  //     R&7 == r16>>1 for all mi/ni (tile bases are multiples of 8 rows).
  const int cgr   = (((r16 & 1) << 2) | g) ^ (r16 >> 1);
  const int aread = (wr * 64 + (r16 >> 1)) * 64 + cgr * 8;           // + mi*512
  const int bread = 8192 + (wcol * 32 + (r16 >> 1)) * 64 + cgr * 8;  // + ni*512

  f32x4 acc[8][4];
  #pragma unroll
  for (int m = 0; m < 8; ++m)
    #pragma unroll
    for (int n = 0; n < 4; ++n)
      #pragma unroll
      for (int j = 0; j < 4; ++j)
        acc[m][n][j] = 0.f;

  short8 af_a[8], bf_a[4], af_b[8], bf_b[4];
  int bcur = 0, bnext = 16384, bstage = 32768;

  // prologue: stage tiles 0,1; ensure tile0 landed (all waves); read frags(0)
  STAGE_T(0, 0);
  STAGE_T(1, 16384);
  asm volatile("s_waitcnt vmcnt(4)" ::: "memory");
  __builtin_amdgcn_s_barrier();
  READ_FRAGS(0, af_a, bf_a);

  #pragma unroll 2
  for (int v = 0; v < KT32; v += 2) {
    TILE(v,     af_a, bf_a, af_b, bf_b);
    TILE(v + 1, af_b, bf_b, af_a, bf_a);
  }

  // ---- fused epilogue: per-row max & sum(exp) over this block's 256 vocab cols ----
  // C/D layout: col = ni*16 + r16, row = mi*16 + g*4 + j
  // stats region = sh[0..4095] (buf0 A): last tile read buf 31%3=1 -> disjoint;
  // all buf0 reads finished before the tile-30 barrier.
  float2 (*stats)[4] = (float2 (*)[4])sh;   // [256][4], 8 KB
  #pragma unroll
  for (int mi = 0; mi < 8; ++mi) {
    #pragma unroll
    for (int j = 0; j < 4; ++j) {
      float vmax = -INFINITY;
      #pragma unroll
      for (int ni = 0; ni < 4; ++ni) {
        const int colg = bn0 + wcol * 64 + ni * 16 + r16;
        float v = (colg < VOCAB) ? acc[mi][ni][j] : -INFINITY;
        vmax = fmaxf(vmax, v);
      }
      vmax = fmaxf(vmax, __shfl_xor(vmax, 1));
      vmax = fmaxf(vmax, __shfl_xor(vmax, 2));
      vmax = fmaxf(vmax, __shfl_xor(vmax, 4));
      vmax = fmaxf(vmax, __shfl_xor(vmax, 8));
      float ssum = 0.f;
      #pragma unroll
      for (int ni = 0; ni < 4; ++ni) {
        const int colg = bn0 + wcol * 64 + ni * 16 + r16;
        if (colg < VOCAB) ssum += __expf(acc[mi][ni][j] - vmax);
      }
      ssum += __shfl_xor(ssum, 1);
      ssum += __shfl_xor(ssum, 2);
      ssum += __shfl_xor(ssum, 4);
      ssum += __shfl_xor(ssum, 8);
      if (r16 == 0) {
        stats[wr * 128 + mi * 16 + g * 4 + j][wcol] = make_float2(vmax, ssum);
      }
    }
  }
  __syncthreads();
  if (tid < 256) {
    float2 a0 = stats[tid][0], a1 = stats[tid][1], a2 = stats[tid][2], a3 = stats[tid][3];
    float M = fmaxf(fmaxf(a0.x, a1.x), fmaxf(a2.x, a3.x));
    float S = a0.y * __expf(a0.x - M) + a1.y * __expf(a1.x - M)
            + a2.y * __expf(a2.x - M) + a3.y * __expf(a3.x - M);
    partials[(long long)(bm0 + tid) * NT + blockIdx.y] = make_float2(M, S);
  }
}

// ---------------- per-row logsumexp + fused target-logit dot --------------------
__global__ void lse_kernel(const float2* __restrict__ partials,
                           const float* __restrict__ x,
                           const float* __restrict__ W,
                           const int* __restrict__ y,
                           float* __restrict__ row_nll) {
  const int n = blockIdx.x * 4 + (threadIdx.x >> 6);   // 1024 blocks x 4 waves
  const int l = threadIdx.x & 63;
  const float2* pr = partials + (long long)n * NT;
  float M = -INFINITY, S = 0.f;
  for (int t = l; t < NT; t += 64) {
    float2 p = pr[t];
    float nM = fmaxf(M, p.x);
    S = S * __expf(M - nM) + p.y * __expf(p.x - nM);
    M = nM;
  }
  const float4* xr = (const float4*)(x + ((long long)n << 10));
  const float4* wv = (const float4*)(W + ((long long)y[n] << 10));
  float dot = 0.f;
  #pragma unroll
  for (int i = 0; i < 4; ++i) {
    float4 a = xr[l + 64 * i];
    float4 b = wv[l + 64 * i];
    dot = fmaf(a.x, b.x, fmaf(a.y, b.y, fmaf(a.z, b.z, fmaf(a.w, b.w, dot))));
  }
  #pragma unroll
  for (int off = 1; off < 64; off <<= 1) {
    float Mo = __shfl_xor(M, off);
    float So = __shfl_xor(S, off);
    float nM = fmaxf(M, Mo);
    S = S * __expf(M - nM) + So * __expf(Mo - nM);
    M = nM;
    dot += __shfl_xor(dot, off);
  }
  if (l == 0) row_nll[n] = (M + logf(S)) - dot;
}

__global__ void mean_kernel(const float* __restrict__ row_nll, float* __restrict__ out) {
  __shared__ float red[4];
  float s = 0.f;
  for (int i = threadIdx.x; i < N_NODES; i += 256) s += row_nll[i];
  #pragma unroll
  for (int m = 32; m; m >>= 1) s += __shfl_xor(s, m, 64);
  if ((threadIdx.x & 63) == 0) red[threadIdx.x >> 6] = s;
  __syncthreads();
  if (threadIdx.x == 0) out[0] = (red[0] + red[1] + red[2] + red[3]) * (1.0f / N_NODES);
}

// ---------------- launcher ------------------------------------------------------
extern "C" void kernel_launch(void* const* d_in, const int* in_sizes, int n_in,
                              void* d_out, int out_size, void* d_ws, size_t ws_size,
                              hipStream_t stream) {
  const float* x = (const float*)d_in[0];
  const float* W = (const float*)d_in[1];
  const int*   y = (const int*)d_in[2];
  float* out = (float*)d_out;

  char* ws = (char*)d_ws;
  unsigned short* Wb = (unsigned short*)ws;                 // VPAD*D*2 = 103,284,736
  unsigned short* Xb = (unsigned short*)(ws + 103284736);   // N*D*2    =   8,388,608
  float2* partials   = (float2*)(ws + 111673344);           // N*NT*8   =   6,455,296
  float* row_nll     = (float*)(ws + 118145024);            // N*4

  hipLaunchKernelGGL(cvt_kernel, dim3(2048), dim3(256), 0, stream, x, W, Xb, Wb);
  hipLaunchKernelGGL(gemm_stats_kernel, dim3(16, NT), dim3(512), 0, stream, Xb, Wb, partials);
  hipLaunchKernelGGL(lse_kernel, dim3(N_NODES / 4), dim3(256), 0, stream, partials, x, W, y, row_nll);
  hipLaunchKernelGGL(mean_kernel, dim3(1), dim3(256), 0, stream, row_nll, out);
}

// Round 11
// 798.071 us; speedup vs baseline: 1.7763x; 1.7763x over previous
//
#include <hip/hip_runtime.h>
#include <hip/hip_bf16.h>
#include <math.h>

// Fused decoder + cross-entropy on MI355X.
//   logits = x @ W^T  (4096 x 50257, K=1024), loss = mean(-log_softmax(logits)[y])
// R10/R11: spill fix + staging-depth experiment.
//   R9 post-mortem: R6's frag ping-pong spilled (WRITE_SIZE 7.7MB -> 1.84GB
//   scratch traffic, gemm 540->1180us). Schedule itself race-verified (absmax 0).
//   R3(552us)/R5(540us) equality across very different schedules + 3.3GB staged
//   / 540us = 6.1 TB/s suggests supply-bound OR staging-depth-bound.
// This round: single frag set (af[8],bf[4], live ~200 regs, no spill),
//   FOUR LDS buffers (128KB), stage 3 tiles ahead, vmcnt(8) = 12 loads in
//   flight/wave (3x latency tolerance of R6), ONE raw s_barrier per K-tile,
//   compiler-scheduled lgkm waits (plain ds_reads interleave into MFMA).
// Safety (deterministic): writer of buf[t%4] = stage(t+4) issued at tile t+1
//   AFTER barrier(t+1); all waves' reads(t) complete before their MFMA(t)
//   (compiler lgkm waits) which precedes barrier(t+1). vmcnt(8)+barrier at
//   tile t proves all waves' stage(t) landed before any wave reads buf[t%4].
// Discriminator: gemm ~400-460us => depth-bound (win); ~540us => BW-bound
//   (3.3GB@6TB/s roofline; next lever = traffic cut, e.g. fp8 W).
// History: R2 964 (gemm 690, 26%); R3 804 (552, 33%); R5 797 (540, 35%);
//   R9 1418 (1180, spill); R10 not run (GPU timeout) — resubmitted unchanged.

#define N_NODES 4096
#define D_EMB   1024
#define VOCAB   50257
#define VPAD    50432   // 197 * 256
#define NT      197     // 256-wide vocab tiles
#define KT32    32      // K-tiles of 32 (1024/32)

typedef __attribute__((ext_vector_type(8))) short short8;   // 8 bf16 (MFMA A/B frag)
typedef __attribute__((ext_vector_type(4))) float f32x4;    // MFMA C/D frag

__device__ __forceinline__ unsigned short f2bf(float f) {
  unsigned int x = __float_as_uint(f);
  x += 0x7fffu + ((x >> 16) & 1u);
  return (unsigned short)(x >> 16);
}

// ---------------- fp32 -> bf16 conversion: x then W (padded), one launch -------
__global__ void cvt_kernel(const float* __restrict__ x, const float* __restrict__ W,
                           unsigned short* __restrict__ Xb, unsigned short* __restrict__ Wb) {
  const long long XG  = (long long)N_NODES * (D_EMB / 8);      // x 16B-groups
  const long long TOT = XG + (long long)VPAD * (D_EMB / 8);    // + W groups
  for (long long gid = (long long)blockIdx.x * 256 + threadIdx.x; gid < TOT;
       gid += (long long)gridDim.x * 256) {
    short8 o;
    if (gid < XG) {
      long long e = gid << 3;
      const float4* p = (const float4*)(x + e);
      float4 u = p[0], v = p[1];
      o[0]=(short)f2bf(u.x); o[1]=(short)f2bf(u.y); o[2]=(short)f2bf(u.z); o[3]=(short)f2bf(u.w);
      o[4]=(short)f2bf(v.x); o[5]=(short)f2bf(v.y); o[6]=(short)f2bf(v.z); o[7]=(short)f2bf(v.w);
      *(short8*)(Xb + e) = o;
    } else {
      long long wg = gid - XG;
      long long e = wg << 3;
      int row = (int)(e >> 10);
      if (row < VOCAB) {
        const float4* p = (const float4*)(W + e);
        float4 u = p[0], v = p[1];
        o[0]=(short)f2bf(u.x); o[1]=(short)f2bf(u.y); o[2]=(short)f2bf(u.z); o[3]=(short)f2bf(u.w);
        o[4]=(short)f2bf(v.x); o[5]=(short)f2bf(v.y); o[6]=(short)f2bf(v.z); o[7]=(short)f2bf(v.w);
      } else {
        o[0]=0;o[1]=0;o[2]=0;o[3]=0;o[4]=0;o[5]=0;o[6]=0;o[7]=0;
      }
      *(short8*)(Wb + e) = o;
    }
  }
}

// ---------------- 256^2 MFMA GEMM, BK=32, 4-buffer, 12-deep staging -------------
#define GLD(SRC, DST)                                                              \
  __builtin_amdgcn_global_load_lds(                                                \
      (const __attribute__((address_space(1))) void*)(SRC),                        \
      (__attribute__((address_space(3))) void*)(DST), 16, 0, 0)

// stage K-tile U (A: 2 gloads, B: 2 gloads) into LDS buffer at elem offset BB
#define STAGE_T(U, BB)                                                             \
  do {                                                                             \
    const int _ko = (U) << 5;                                                      \
    GLD(Xb + aoff0 + _ko,          sh + (BB) + dstA);                              \
    GLD(Xb + aoff0 + 131072 + _ko, sh + (BB) + 4096 + dstA);                       \
    GLD(Wb + boff0 + _ko,          sh + (BB) + 8192 + dstA);                       \
    GLD(Wb + boff0 + 131072 + _ko, sh + (BB) + 12288 + dstA);                      \
  } while (0)

#define READ_FRAGS(BB)                                                             \
  do {                                                                             \
    const unsigned short* _A = sh + (BB) + aread;                                  \
    const unsigned short* _B = sh + (BB) + bread;                                  \
    _Pragma("unroll")                                                              \
    for (int ni = 0; ni < 4; ++ni) bf[ni] = *(const short8*)(_B + ni * 512);       \
    _Pragma("unroll")                                                              \
    for (int mi = 0; mi < 8; ++mi) af[mi] = *(const short8*)(_A + mi * 512);       \
  } while (0)

#define MFMA32()                                                                   \
  do {                                                                             \
    _Pragma("unroll")                                                              \
    for (int mi = 0; mi < 8; ++mi)                                                 \
      _Pragma("unroll")                                                            \
      for (int ni = 0; ni < 4; ++ni)                                               \
        acc[mi][ni] = __builtin_amdgcn_mfma_f32_16x16x32_bf16(af[mi], bf[ni], acc[mi][ni], 0, 0, 0); \
  } while (0)

// one K-tile. VMN: vmcnt immediate (8 steady / 4,0 tail). DO_STG: stage t+3?
// BRD: read-buffer base (elems, = (U%4)*16384). BST: stage buffer ((U+3)%4)*16384.
#define TILE_N(U, VMN, DO_STG, BRD, BST)                                           \
  do {                                                                             \
    asm volatile("s_waitcnt vmcnt(" #VMN ")" ::: "memory");                        \
    __builtin_amdgcn_s_barrier();                                                  \
    if (DO_STG) STAGE_T((U) + 3, BST);                                             \
    short8 af[8], bf[4];                                                           \
    READ_FRAGS(BRD);                                                               \
    __builtin_amdgcn_s_setprio(1);                                                 \
    MFMA32();                                                                      \
    __builtin_amdgcn_s_setprio(0);                                                 \
  } while (0)

__global__ __launch_bounds__(512, 2) void gemm_stats_kernel(
    const unsigned short* __restrict__ Xb,
    const unsigned short* __restrict__ Wb,
    float2* __restrict__ partials)  // [N_NODES][NT]: (rowmax, sumexp) per vocab tile
{
  __shared__ __align__(16) unsigned short sh[65536];  // 128 KB = 4 x (A 16K + B 16K)

  const int tid  = threadIdx.x;
  const int lane = tid & 63;
  const int wid  = tid >> 6;    // 0..7
  const int wr   = wid >> 2;    // 0..1: rows wr*128..
  const int wcol = wid & 3;     // 0..3: cols wcol*64..
  const int g    = lane >> 4;   // 0..3
  const int r16  = lane & 15;

  const int bm0 = blockIdx.x * 256;
  const int bn0 = blockIdx.y * 256;

  // --- staging geometry: LDS [128][64] paired-row; slot (R,cg) holds global
  //     (row (R<<1)|(cgu>>2), col (cgu&3)*8) with cgu = cg ^ (R&7).  (R6-verified)
  const int cgu   = (tid & 7) ^ ((tid >> 3) & 7);
  const int rl0   = ((tid >> 3) << 1) | (cgu >> 2);
  const int cgc   = (cgu & 3) << 3;
  const int aoff0 = (bm0 + rl0) * D_EMB + cgc;     // + 131072 for p=1 (+128 rows)
  const int boff0 = (bn0 + rl0) * D_EMB + cgc;
  const int dstA  = tid * 8;                       // + p*4096; B region +8192

  // --- fragment-read geometry (R6-verified): row ar -> R=ar>>1, cg=((ar&1)*4+g)^(R&7)
  const int cgr   = (((r16 & 1) << 2) | g) ^ (r16 >> 1);
  const int aread = (wr * 64 + (r16 >> 1)) * 64 + cgr * 8;           // + mi*512
  const int bread = 8192 + (wcol * 32 + (r16 >> 1)) * 64 + cgr * 8;  // + ni*512

  f32x4 acc[8][4];
  #pragma unroll
  for (int m = 0; m < 8; ++m)
    #pragma unroll
    for (int n = 0; n < 4; ++n)
      #pragma unroll
      for (int j = 0; j < 4; ++j)
        acc[m][n][j] = 0.f;

  // prologue: stage tiles 0,1,2 into bufs 0,1,2 (12 loads in flight)
  STAGE_T(0, 0);
  STAGE_T(1, 16384);
  STAGE_T(2, 32768);

  // main loop: tiles 0..27 in groups of 4 (buffer cycle static per slot)
  for (int v = 0; v < KT32 - 4; v += 4) {
    TILE_N(v,     8, 1, 0,     49152);   // read buf0, stage -> buf3
    TILE_N(v + 1, 8, 1, 16384, 0);       // read buf1, stage -> buf0
    TILE_N(v + 2, 8, 1, 32768, 16384);   // read buf2, stage -> buf1
    TILE_N(v + 3, 8, 1, 49152, 32768);   // read buf3, stage -> buf2
  }
  // tail: tiles 28..31 (stage(31) at t=28 only; vmcnt tapers 8,8,4,0)
  TILE_N(28, 8, 1, 0,     49152);
  TILE_N(29, 8, 0, 16384, 0);
  TILE_N(30, 4, 0, 32768, 0);
  TILE_N(31, 0, 0, 49152, 0);

  // ---- fused epilogue: per-row max & sum(exp) over this block's 256 vocab cols ----
  // C/D layout: col = ni*16 + r16, row = mi*16 + g*4 + j
  // stats region aliases buf0 (last buf0 reads at tile 28, complete before
  // barrier(29); every wave passed barrier(31) before reaching here).
  float2 (*stats)[4] = (float2 (*)[4])sh;   // [256][4], 8 KB
  #pragma unroll
  for (int mi = 0; mi < 8; ++mi) {
    #pragma unroll
    for (int j = 0; j < 4; ++j) {
      float vmax = -INFINITY;
      #pragma unroll
      for (int ni = 0; ni < 4; ++ni) {
        const int colg = bn0 + wcol * 64 + ni * 16 + r16;
        float v = (colg < VOCAB) ? acc[mi][ni][j] : -INFINITY;
        vmax = fmaxf(vmax, v);
      }
      vmax = fmaxf(vmax, __shfl_xor(vmax, 1));
      vmax = fmaxf(vmax, __shfl_xor(vmax, 2));
      vmax = fmaxf(vmax, __shfl_xor(vmax, 4));
      vmax = fmaxf(vmax, __shfl_xor(vmax, 8));
      float ssum = 0.f;
      #pragma unroll
      for (int ni = 0; ni < 4; ++ni) {
        const int colg = bn0 + wcol * 64 + ni * 16 + r16;
        if (colg < VOCAB) ssum += __expf(acc[mi][ni][j] - vmax);
      }
      ssum += __shfl_xor(ssum, 1);
      ssum += __shfl_xor(ssum, 2);
      ssum += __shfl_xor(ssum, 4);
      ssum += __shfl_xor(ssum, 8);
      if (r16 == 0) {
        stats[wr * 128 + mi * 16 + g * 4 + j][wcol] = make_float2(vmax, ssum);
      }
    }
  }
  __syncthreads();
  if (tid < 256) {
    float2 a0 = stats[tid][0], a1 = stats[tid][1], a2 = stats[tid][2], a3 = stats[tid][3];
    float M = fmaxf(fmaxf(a0.x, a1.x), fmaxf(a2.x, a3.x));
    float S = a0.y * __expf(a0.x - M) + a1.y * __expf(a1.x - M)
            + a2.y * __expf(a2.x - M) + a3.y * __expf(a3.x - M);
    partials[(long long)(bm0 + tid) * NT + blockIdx.y] = make_float2(M, S);
  }
}

// ---------------- per-row logsumexp + fused target-logit dot --------------------
__global__ void lse_kernel(const float2* __restrict__ partials,
                           const float* __restrict__ x,
                           const float* __restrict__ W,
                           const int* __restrict__ y,
                           float* __restrict__ row_nll) {
  const int n = blockIdx.x * 4 + (threadIdx.x >> 6);   // 1024 blocks x 4 waves
  const int l = threadIdx.x & 63;
  const float2* pr = partials + (long long)n * NT;
  float M = -INFINITY, S = 0.f;
  for (int t = l; t < NT; t += 64) {
    float2 p = pr[t];
    float nM = fmaxf(M, p.x);
    S = S * __expf(M - nM) + p.y * __expf(p.x - nM);
    M = nM;
  }
  const float4* xr = (const float4*)(x + ((long long)n << 10));
  const float4* wv = (const float4*)(W + ((long long)y[n] << 10));
  float dot = 0.f;
  #pragma unroll
  for (int i = 0; i < 4; ++i) {
    float4 a = xr[l + 64 * i];
    float4 b = wv[l + 64 * i];
    dot = fmaf(a.x, b.x, fmaf(a.y, b.y, fmaf(a.z, b.z, fmaf(a.w, b.w, dot))));
  }
  #pragma unroll
  for (int off = 1; off < 64; off <<= 1) {
    float Mo = __shfl_xor(M, off);
    float So = __shfl_xor(S, off);
    float nM = fmaxf(M, Mo);
    S = S * __expf(M - nM) + So * __expf(Mo - nM);
    M = nM;
    dot += __shfl_xor(dot, off);
  }
  if (l == 0) row_nll[n] = (M + logf(S)) - dot;
}

__global__ void mean_kernel(const float* __restrict__ row_nll, float* __restrict__ out) {
  __shared__ float red[4];
  float s = 0.f;
  for (int i = threadIdx.x; i < N_NODES; i += 256) s += row_nll[i];
  #pragma unroll
  for (int m = 32; m; m >>= 1) s += __shfl_xor(s, m, 64);
  if ((threadIdx.x & 63) == 0) red[threadIdx.x >> 6] = s;
  __syncthreads();
  if (threadIdx.x == 0) out[0] = (red[0] + red[1] + red[2] + red[3]) * (1.0f / N_NODES);
}

// ---------------- launcher ------------------------------------------------------
extern "C" void kernel_launch(void* const* d_in, const int* in_sizes, int n_in,
                              void* d_out, int out_size, void* d_ws, size_t ws_size,
                              hipStream_t stream) {
  const float* x = (const float*)d_in[0];
  const float* W = (const float*)d_in[1];
  const int*   y = (const int*)d_in[2];
  float* out = (float*)d_out;

  char* ws = (char*)d_ws;
  unsigned short* Wb = (unsigned short*)ws;                 // VPAD*D*2 = 103,284,736
  unsigned short* Xb = (unsigned short*)(ws + 103284736);   // N*D*2    =   8,388,608
  float2* partials   = (float2*)(ws + 111673344);           // N*NT*8   =   6,455,296
  float* row_nll     = (float*)(ws + 118145024);            // N*4

  hipLaunchKernelGGL(cvt_kernel, dim3(2048), dim3(256), 0, stream, x, W, Xb, Wb);
  hipLaunchKernelGGL(gemm_stats_kernel, dim3(16, NT), dim3(512), 0, stream, Xb, Wb, partials);
  hipLaunchKernelGGL(lse_kernel, dim3(N_NODES / 4), dim3(256), 0, stream, partials, x, W, y, row_nll);
  hipLaunchKernelGGL(mean_kernel, dim3(1), dim3(256), 0, stream, row_nll, out);
}